// Round 7
// baseline (133.028 us; speedup 1.0000x reference)
//
#include <hip/hip_runtime.h>
#include <stdint.h>

#define IN_DIM 2048
#define OUT_DIM 2048
#define BATCH 4096
#define KDIM (2 * IN_DIM)   // 4096
#define KROWB (KDIM * 2)    // 8192 bytes per bf16 row
#define KH 2048             // K-half (split-K=2)
#define NTT 32              // K-tiles of 64 per half
#define BN_EPS 1e-5f

typedef __attribute__((ext_vector_type(8))) short bf16x8;
typedef __attribute__((ext_vector_type(4))) float f32x4;

__device__ __forceinline__ unsigned short f2bf(float f) {
  union { float f; unsigned u; } v; v.f = f;
  unsigned r = v.u + 0x7FFFu + ((v.u >> 16) & 1u);  // RNE
  return (unsigned short)(r >> 16);
}

// K1a: A = [wavelet(x) | x] bf16, row-major (BATCH x KDIM)
__global__ void prep_act(const float* __restrict__ x,
                         const float* __restrict__ scale,
                         const float* __restrict__ translate,
                         unsigned short* __restrict__ A) {
  int e = (blockIdx.x * 256 + threadIdx.x) * 4;
  int b = e / IN_DIM;
  int i = e % IN_DIM;
  float4 xv = *(const float4*)(x + e);
  float4 sv = *(const float4*)(scale + i);
  float4 tv = *(const float4*)(translate + i);
  const float c = 0.7511255444649425f;  // pi^-0.25
  float u0 = (xv.x - tv.x) / fmaxf(sv.x, 1e-3f);
  float u1 = (xv.y - tv.y) / fmaxf(sv.y, 1e-3f);
  float u2 = (xv.z - tv.z) / fmaxf(sv.z, 1e-3f);
  float u3 = (xv.w - tv.w) / fmaxf(sv.w, 1e-3f);
  ushort4 wv, xb;
  wv.x = f2bf(c * __cosf(3.0f * u0) * __expf(-0.5f * u0 * u0));
  wv.y = f2bf(c * __cosf(3.0f * u1) * __expf(-0.5f * u1 * u1));
  wv.z = f2bf(c * __cosf(3.0f * u2) * __expf(-0.5f * u2 * u2));
  wv.w = f2bf(c * __cosf(3.0f * u3) * __expf(-0.5f * u3 * u3));
  xb.x = f2bf(xv.x); xb.y = f2bf(xv.y); xb.z = f2bf(xv.z); xb.w = f2bf(xv.w);
  *(ushort4*)(A + (size_t)b * KDIM + i) = wv;
  *(ushort4*)(A + (size_t)b * KDIM + IN_DIM + i) = xb;
}

// K1b: W = [wave_weight | 0.3*base_weight] bf16, row-major (OUT_DIM x KDIM)
__global__ void prep_w(const float* __restrict__ ww,
                       const float* __restrict__ bw,
                       unsigned short* __restrict__ W) {
  int e = (blockIdx.x * 256 + threadIdx.x) * 4;
  int o = e / IN_DIM;
  int k = e % IN_DIM;
  float4 a = *(const float4*)(ww + e);
  float4 b = *(const float4*)(bw + e);
  ushort4 wa, wb;
  wa.x = f2bf(a.x); wa.y = f2bf(a.y); wa.z = f2bf(a.z); wa.w = f2bf(a.w);
  wb.x = f2bf(0.3f * b.x); wb.y = f2bf(0.3f * b.y);
  wb.z = f2bf(0.3f * b.z); wb.w = f2bf(0.3f * b.w);
  *(ushort4*)(W + (size_t)o * KDIM + k) = wa;
  *(ushort4*)(W + (size_t)o * KDIM + IN_DIM + k) = wb;
}

// ---- split-K 256x256 GEMM, BK=64, m201-style 4-phase/tile schedule ----
// LDS 128KB = 2 parities x 64KB: {A-h0 @0, A-h1 @16K, B-h0 @32K, B-h1 @48K}.
// Row storage: row*128B, 16B slot pos = kslot ^ (row&7)  [XOR swizzle, both
// sides: pre-swizzled global source + swizzled ds_read].
// Stage ledger (2 GLDS per half-unit): p1 stages A-h1(t+1) [region last read
// at p4(t-1), behind a barrier]; p4 stages {A-h0,B-h0,B-h1}(t+2) [same parity
// as t, regions last read at p3(t), behind p3's barrier]. vmcnt(6) at p4-end:
// outstanding = [p4(t-1):6]+[p1(t):2]+[p4(t):6] -> drains exactly tile t+1's
// 8 loads (3-4 phases old). Prologue: 14 loads, vmcnt(6).

#define GLDS(gp, lo) __builtin_amdgcn_global_load_lds( \
    (const __attribute__((address_space(1))) void*)(gp), \
    (__attribute__((address_space(3))) void*)(lds + (lo) + ldsl), 16, 0, 0)

#define STG2(gp_, lo_) do { \
  GLDS((gp_), (lo_)); \
  GLDS((gp_) + (size_t)64 * KROWB, (lo_) + 8192); \
} while (0)

#define LDA(mh, ro) do { \
  af[0] = *(const bf16x8*)(lds + P + AuO + (mh) * 8192 + 0 * 2048 + (ro)); \
  af[1] = *(const bf16x8*)(lds + P + AuO + (mh) * 8192 + 1 * 2048 + (ro)); \
  af[2] = *(const bf16x8*)(lds + P + AuO + (mh) * 8192 + 2 * 2048 + (ro)); \
  af[3] = *(const bf16x8*)(lds + P + AuO + (mh) * 8192 + 3 * 2048 + (ro)); \
} while (0)

#define LDB(dst, ro) do { \
  dst[0] = *(const bf16x8*)(lds + P + BuO + 0 * 2048 + (ro)); \
  dst[1] = *(const bf16x8*)(lds + P + BuO + 1 * 2048 + (ro)); \
  dst[2] = *(const bf16x8*)(lds + P + BuO + 2 * 2048 + (ro)); \
  dst[3] = *(const bf16x8*)(lds + P + BuO + 3 * 2048 + (ro)); \
} while (0)

#define MM16(mh, bq) do { \
  __builtin_amdgcn_s_setprio(1); \
  _Pragma("unroll") for (int i2 = 0; i2 < 4; ++i2) \
  _Pragma("unroll") for (int j2 = 0; j2 < 4; ++j2) \
    acc[(mh) * 4 + i2][j2] = __builtin_amdgcn_mfma_f32_16x16x32_bf16( \
        af[i2], bq[j2], acc[(mh) * 4 + i2][j2], 0, 0, 0); \
  __builtin_amdgcn_s_setprio(0); \
} while (0)

#define LGKM0() asm volatile("s_waitcnt lgkmcnt(0)" ::: "memory")
#define VMW6()  asm volatile("s_waitcnt vmcnt(6)" ::: "memory")
#define VMW0()  asm volatile("s_waitcnt vmcnt(0)" ::: "memory")
#define NOW()   do { } while (0)
#define BAR()   do { asm volatile("" ::: "memory"); __builtin_amdgcn_s_barrier(); \
                     asm volatile("" ::: "memory"); } while (0)

#define KTILE(m, DO1, DO4, TAILW) do { \
  const int P = ((m) & 1) << 16; \
  const int Q = P ^ 65536; \
  /* p1 */ \
  LDA(0, ro0); LDB(b0, ro0); \
  if (DO1) STG2(aP1 + (size_t)((m) + 1) * 128, Q + 16384); \
  BAR(); LGKM0(); MM16(0, b0); BAR(); \
  /* p2 */ \
  LDA(1, ro0); \
  BAR(); LGKM0(); MM16(1, b0); BAR(); \
  /* p3 */ \
  LDA(0, ro1); LDB(b1, ro1); \
  BAR(); LGKM0(); MM16(0, b1); BAR(); \
  /* p4 */ \
  LDA(1, ro1); \
  if (DO4) { STG2(aP0 + (size_t)((m) + 2) * 128, P); \
             STG2(bP0 + (size_t)((m) + 2) * 128, P + 32768); \
             STG2(bP1 + (size_t)((m) + 2) * 128, P + 49152); } \
  BAR(); LGKM0(); MM16(1, b1); TAILW; BAR(); \
} while (0)

__global__ __launch_bounds__(512, 2) void gemm256(
    const unsigned short* __restrict__ A,
    const unsigned short* __restrict__ W,
    float* __restrict__ P0, float* __restrict__ P1) {
  __shared__ char lds[131072];
  const int tid = threadIdx.x;
  const int lane = tid & 63;
  const int wave = tid >> 6;
  const int wm = wave >> 2;   // 0..1 -> 128-row M half
  const int wn = wave & 3;    // 0..3 -> 64-col N quarter

  // XCD-aware bijective swizzle (256 blocks, %8==0); sw = [kz:1][m:4][n:3]
  const int sw = ((blockIdx.x & 7) << 5) | (blockIdx.x >> 3);
  const int kz = sw >> 7;
  const int brow = ((sw >> 3) & 15) * 256;
  const int bcol = (sw & 7) * 256;
  const size_t kb = (size_t)kz * (KH * 2);  // byte offset of K-half

  // staging: thread tid covers unit byte tid*16 per round; that slot holds
  // global (row = tid>>3 [+64 round 1], kslot = (tid&7) ^ ((tid>>3)&7)).
  const int srow = tid >> 3;
  const int skslot = (tid & 7) ^ (srow & 7);
  const char* aP0 = (const char*)A + (size_t)(brow + srow) * KROWB + kb + skslot * 16;
  const char* aP1 = aP0 + (size_t)128 * KROWB;
  const char* bP0 = (const char*)W + (size_t)(bcol + srow) * KROWB + kb + skslot * 16;
  const char* bP1 = bP0 + (size_t)128 * KROWB;
  const int ldsl = wave * 1024;  // + lane*16 implicit in global_load_lds

  // fragment read: row = f*16 + (lane&15), kslot = (lane>>4) + 4*ks
  // byte = row*128 + ((kslot ^ (row&7))<<4); row&7 == lane&7 for all f
  const int ro0 = (lane & 15) * 128 + ((((lane >> 4)    ) ^ (lane & 7)) << 4);
  const int ro1 = (lane & 15) * 128 + ((((lane >> 4) + 4) ^ (lane & 7)) << 4);
  const int AuO = wm * 16384;
  const int BuO = 32768 + (wn >> 1) * 16384 + (wn & 1) * 8192;

  f32x4 acc[8][4];
#pragma unroll
  for (int m = 0; m < 8; ++m)
#pragma unroll
    for (int n = 0; n < 4; ++n)
      acc[m][n] = (f32x4){0.f, 0.f, 0.f, 0.f};
  bf16x8 af[4], b0[4], b1[4];

  // prologue: T0 complete (8) + T1 {A-h0, B-h0, B-h1} (6); vmcnt(6) -> T0 in
  STG2(aP0, 0); STG2(aP1, 16384); STG2(bP0, 32768); STG2(bP1, 49152);
  STG2(aP0 + 128, 65536);
  STG2(bP0 + 128, 65536 + 32768);
  STG2(bP1 + 128, 65536 + 49152);
  VMW6(); BAR();

  for (int m = 0; m < NTT - 2; ++m)
    KTILE(m, 1, 1, VMW6());
  KTILE(NTT - 2, 1, 0, VMW0());
  KTILE(NTT - 1, 0, 0, NOW());

  float* Pz = kz ? P1 : P0;
  const int r0 = brow + wm * 128 + (lane >> 4) * 4;
  const int c0 = bcol + wn * 64 + (lane & 15);
#pragma unroll
  for (int m = 0; m < 8; ++m)
#pragma unroll
    for (int n = 0; n < 4; ++n)
#pragma unroll
      for (int j = 0; j < 4; ++j)
        Pz[(size_t)(r0 + m * 16 + j) * OUT_DIM + (c0 + n * 16)] = acc[m][n][j];
}

// K3a: per-column stats over y = P0+P1 (CORRECT: squares the sum), float4
__global__ void colstats2(const float* __restrict__ P0,
                          const float* __restrict__ P1,
                          float* __restrict__ sums, float* __restrict__ sqs) {
  // grid 256: c4 = (b&1)*256 + tid (512 col4 groups), rows (b>>1)*32 .. +32
  int c4 = (blockIdx.x & 1) * 256 + threadIdx.x;
  int r0 = (blockIdx.x >> 1) * 32;
  float4 s = {0.f, 0.f, 0.f, 0.f}, q = {0.f, 0.f, 0.f, 0.f};
  for (int r = 0; r < 32; ++r) {
    size_t idx = (size_t)(r0 + r) * (OUT_DIM / 4) + c4;
    float4 a = ((const float4*)P0)[idx];
    float4 b = ((const float4*)P1)[idx];
    float v0 = a.x + b.x, v1 = a.y + b.y, v2 = a.z + b.z, v3 = a.w + b.w;
    s.x += v0; s.y += v1; s.z += v2; s.w += v3;
    q.x += v0 * v0; q.y += v1 * v1; q.z += v2 * v2; q.w += v3 * v3;
  }
  atomicAdd(&sums[c4 * 4 + 0], s.x); atomicAdd(&sums[c4 * 4 + 1], s.y);
  atomicAdd(&sums[c4 * 4 + 2], s.z); atomicAdd(&sums[c4 * 4 + 3], s.w);
  atomicAdd(&sqs[c4 * 4 + 0], q.x); atomicAdd(&sqs[c4 * 4 + 1], q.y);
  atomicAdd(&sqs[c4 * 4 + 2], q.z); atomicAdd(&sqs[c4 * 4 + 3], q.w);
}

// K3b: fused partial-add + batchnorm, Y (=P0=d_out) in-place
__global__ void bnorm2(const float* __restrict__ P1, float* __restrict__ Y,
                       const float* __restrict__ sums, const float* __restrict__ sqs,
                       const float* __restrict__ gamma, const float* __restrict__ beta) {
  int e = (blockIdx.x * 256 + threadIdx.x) * 4;
  int c = e % OUT_DIM;
  float4 y = *(float4*)(Y + e);
  float4 p = *(const float4*)(P1 + e);
  y.x += p.x; y.y += p.y; y.z += p.z; y.w += p.w;
  float4 s = *(const float4*)(sums + c);
  float4 q = *(const float4*)(sqs + c);
  float4 g = *(const float4*)(gamma + c);
  float4 bb = *(const float4*)(beta + c);
  const float invB = 1.0f / (float)BATCH;
  float m0 = s.x * invB, m1 = s.y * invB, m2 = s.z * invB, m3 = s.w * invB;
  float i0 = rsqrtf(q.x * invB - m0 * m0 + BN_EPS);
  float i1 = rsqrtf(q.y * invB - m1 * m1 + BN_EPS);
  float i2 = rsqrtf(q.z * invB - m2 * m2 + BN_EPS);
  float i3 = rsqrtf(q.w * invB - m3 * m3 + BN_EPS);
  y.x = g.x * (y.x - m0) * i0 + bb.x;
  y.y = g.y * (y.y - m1) * i1 + bb.y;
  y.z = g.z * (y.z - m2) * i2 + bb.z;
  y.w = g.w * (y.w - m3) * i3 + bb.w;
  *(float4*)(Y + e) = y;
}

extern "C" void kernel_launch(void* const* d_in, const int* in_sizes, int n_in,
                              void* d_out, int out_size, void* d_ws, size_t ws_size,
                              hipStream_t stream) {
  const float* x         = (const float*)d_in[0];
  const float* scale     = (const float*)d_in[1];
  const float* translate = (const float*)d_in[2];
  const float* ww        = (const float*)d_in[3];
  const float* bw        = (const float*)d_in[4];
  const float* gamma     = (const float*)d_in[5];
  const float* beta      = (const float*)d_in[6];
  float* out = (float*)d_out;

  char* ws = (char*)d_ws;
  unsigned short* A = (unsigned short*)ws;                 // 33,554,432 B
  unsigned short* W = (unsigned short*)(ws + 33554432);    // 16,777,216 B
  float* P1   = (float*)(ws + 50331648);                   // 33,554,432 B
  float* sums = (float*)(ws + 83886080);
  float* sqs  = sums + OUT_DIM;

  hipMemsetAsync(sums, 0, 2 * OUT_DIM * sizeof(float), stream);
  prep_act<<<(BATCH * IN_DIM) / 1024, 256, 0, stream>>>(x, scale, translate, A);
  prep_w<<<(OUT_DIM * IN_DIM) / 1024, 256, 0, stream>>>(ww, bw, W);
  gemm256<<<256, 512, 0, stream>>>(A, W, out, P1);
  colstats2<<<256, 256, 0, stream>>>(out, P1, sums, sqs);
  bnorm2<<<(BATCH * OUT_DIM) / 1024, 256, 0, stream>>>(P1, out, sums, sqs, gamma, beta);
}

// Round 8
// 114.507 us; speedup vs baseline: 1.1617x; 1.1617x over previous
//
#include <hip/hip_runtime.h>
#include <stdint.h>

#define IN_DIM 2048
#define OUT_DIM 2048
#define BATCH 4096
#define KDIM (2 * IN_DIM)   // 4096
#define KROWB (KDIM * 2)    // 8192 bytes per bf16 row
#define BN_EPS 1e-5f

typedef __attribute__((ext_vector_type(8))) short bf16x8;
typedef __attribute__((ext_vector_type(16))) float f32x16;

__device__ __forceinline__ unsigned short f2bf(float f) {
  union { float f; unsigned u; } v; v.f = f;
  unsigned r = v.u + 0x7FFFu + ((v.u >> 16) & 1u);  // RNE
  return (unsigned short)(r >> 16);
}

// K1a: A = [wavelet(x) | x] bf16, row-major (BATCH x KDIM)
__global__ void prep_act(const float* __restrict__ x,
                         const float* __restrict__ scale,
                         const float* __restrict__ translate,
                         unsigned short* __restrict__ A) {
  int e = (blockIdx.x * 256 + threadIdx.x) * 4;
  int b = e / IN_DIM;
  int i = e % IN_DIM;
  float4 xv = *(const float4*)(x + e);
  float4 sv = *(const float4*)(scale + i);
  float4 tv = *(const float4*)(translate + i);
  const float c = 0.7511255444649425f;  // pi^-0.25
  float u0 = (xv.x - tv.x) / fmaxf(sv.x, 1e-3f);
  float u1 = (xv.y - tv.y) / fmaxf(sv.y, 1e-3f);
  float u2 = (xv.z - tv.z) / fmaxf(sv.z, 1e-3f);
  float u3 = (xv.w - tv.w) / fmaxf(sv.w, 1e-3f);
  ushort4 wv, xb;
  wv.x = f2bf(c * __cosf(3.0f * u0) * __expf(-0.5f * u0 * u0));
  wv.y = f2bf(c * __cosf(3.0f * u1) * __expf(-0.5f * u1 * u1));
  wv.z = f2bf(c * __cosf(3.0f * u2) * __expf(-0.5f * u2 * u2));
  wv.w = f2bf(c * __cosf(3.0f * u3) * __expf(-0.5f * u3 * u3));
  xb.x = f2bf(xv.x); xb.y = f2bf(xv.y); xb.z = f2bf(xv.z); xb.w = f2bf(xv.w);
  *(ushort4*)(A + (size_t)b * KDIM + i) = wv;
  *(ushort4*)(A + (size_t)b * KDIM + IN_DIM + i) = xb;
}

// K1b: W = [wave_weight | 0.3*base_weight] bf16, row-major (OUT_DIM x KDIM)
__global__ void prep_w(const float* __restrict__ ww,
                       const float* __restrict__ bw,
                       unsigned short* __restrict__ W) {
  int e = (blockIdx.x * 256 + threadIdx.x) * 4;
  int o = e / IN_DIM;
  int k = e % IN_DIM;
  float4 a = *(const float4*)(ww + e);
  float4 b = *(const float4*)(bw + e);
  ushort4 wa, wb;
  wa.x = f2bf(a.x); wa.y = f2bf(a.y); wa.z = f2bf(a.z); wa.w = f2bf(a.w);
  wb.x = f2bf(0.3f * b.x); wb.y = f2bf(0.3f * b.y);
  wb.z = f2bf(0.3f * b.z); wb.w = f2bf(0.3f * b.w);
  *(ushort4*)(W + (size_t)o * KDIM + k) = wa;
  *(ushort4*)(W + (size_t)o * KDIM + IN_DIM + k) = wb;
}

// ---- full-K 128x256 GEMM, 4 waves of 64x128, 32x32x16 MFMA, BK=64 ----
// 3-slot LDS ring, slot 48KB: A @0 (128 rows x 128B), B @16384 (256 x 128B).
// Row storage: byte = row*128 + ((kslot ^ (row&7))<<4)  [XOR swizzle, both
// sides]. Tile t reads slot t%3, stages tile t+2 into slot (t+2)%3 (disjoint
// from t and t+1). FIFO (12 GLDS/thread/tile): vmcnt(12) at tile end drains
// exactly tile t+1's loads (issued 1 tile = ~1400cyc earlier). ONE barrier
// per tile (lgkmcnt(0) first, so no in-flight ds_reads on slot reuse).

#define GLDS(gp, lo) __builtin_amdgcn_global_load_lds( \
    (const __attribute__((address_space(1))) void*)(gp), \
    (__attribute__((address_space(3))) void*)(lds + (lo) + ldsw), 16, 0, 0)

#define STAGE(SS, ap_, bp_) do { \
  GLDS((ap_),                (SS) * 49152 + 0); \
  GLDS((ap_) +  32 * KROWB,  (SS) * 49152 + 4096); \
  GLDS((ap_) +  64 * KROWB,  (SS) * 49152 + 8192); \
  GLDS((ap_) +  96 * KROWB,  (SS) * 49152 + 12288); \
  GLDS((bp_),                (SS) * 49152 + 16384); \
  GLDS((bp_) +  32 * KROWB,  (SS) * 49152 + 20480); \
  GLDS((bp_) +  64 * KROWB,  (SS) * 49152 + 24576); \
  GLDS((bp_) +  96 * KROWB,  (SS) * 49152 + 28672); \
  GLDS((bp_) + 128 * KROWB,  (SS) * 49152 + 32768); \
  GLDS((bp_) + 160 * KROWB,  (SS) * 49152 + 36864); \
  GLDS((bp_) + 192 * KROWB,  (SS) * 49152 + 40960); \
  GLDS((bp_) + 224 * KROWB,  (SS) * 49152 + 45056); \
} while (0)

#define LD6(S, sxv) do { \
  af0 = *(const bf16x8*)(lds + (S) * 49152 + ard + (sxv)); \
  af1 = *(const bf16x8*)(lds + (S) * 49152 + ard + 4096 + (sxv)); \
  bq0 = *(const bf16x8*)(lds + (S) * 49152 + brd + (sxv)); \
  bq1 = *(const bf16x8*)(lds + (S) * 49152 + brd + 4096 + (sxv)); \
  bq2 = *(const bf16x8*)(lds + (S) * 49152 + brd + 8192 + (sxv)); \
  bq3 = *(const bf16x8*)(lds + (S) * 49152 + brd + 12288 + (sxv)); \
} while (0)

#define MM8() do { \
  acc[0][0] = __builtin_amdgcn_mfma_f32_32x32x16_bf16(af0, bq0, acc[0][0], 0, 0, 0); \
  acc[0][1] = __builtin_amdgcn_mfma_f32_32x32x16_bf16(af0, bq1, acc[0][1], 0, 0, 0); \
  acc[0][2] = __builtin_amdgcn_mfma_f32_32x32x16_bf16(af0, bq2, acc[0][2], 0, 0, 0); \
  acc[0][3] = __builtin_amdgcn_mfma_f32_32x32x16_bf16(af0, bq3, acc[0][3], 0, 0, 0); \
  acc[1][0] = __builtin_amdgcn_mfma_f32_32x32x16_bf16(af1, bq0, acc[1][0], 0, 0, 0); \
  acc[1][1] = __builtin_amdgcn_mfma_f32_32x32x16_bf16(af1, bq1, acc[1][1], 0, 0, 0); \
  acc[1][2] = __builtin_amdgcn_mfma_f32_32x32x16_bf16(af1, bq2, acc[1][2], 0, 0, 0); \
  acc[1][3] = __builtin_amdgcn_mfma_f32_32x32x16_bf16(af1, bq3, acc[1][3], 0, 0, 0); \
} while (0)

#define LGKM0() asm volatile("s_waitcnt lgkmcnt(0)" ::: "memory")
#define VMW12() asm volatile("s_waitcnt vmcnt(12)" ::: "memory")
#define VMW0()  asm volatile("s_waitcnt vmcnt(0)" ::: "memory")
#define NOW()   do { } while (0)
#define BAR()   do { asm volatile("" ::: "memory"); __builtin_amdgcn_s_barrier(); \
                     asm volatile("" ::: "memory"); } while (0)

#define KT(S, SS, ap_, bp_, DOST, TAILW) do { \
  LD6(S, sx0); \
  if (DOST) STAGE(SS, ap_, bp_); \
  MM8(); \
  LD6(S, sx1); MM8(); \
  LD6(S, sx2); MM8(); \
  LD6(S, sx3); MM8(); \
  LGKM0(); TAILW; BAR(); \
} while (0)

__global__ __launch_bounds__(256, 1) void gemm128x256(
    const unsigned short* __restrict__ A,
    const unsigned short* __restrict__ W,
    float* __restrict__ Y,
    float* __restrict__ sums, float* __restrict__ sqs) {
  __shared__ char lds[147456];
  const int tid = threadIdx.x;
  const int lane = tid & 63;
  const int wave = tid >> 6;
  const int wm = wave >> 1;   // 0..1 -> 64-row M half
  const int wn = wave & 1;    // 0..1 -> 128-col N half

  // XCD-aware bijective swizzle (256 blocks, %8==0). XCD x gets one 2MB
  // B-panel (n = x, L2-resident) and streams all 32 A-panels from L3.
  const int sw = ((blockIdx.x & 7) << 5) | (blockIdx.x >> 3);
  const int brow = (sw & 31) * 128;
  const int bcol = (sw >> 5) * 256;

  // staging: thread tid covers LDS unit byte tid*16 (+i*4096); that slot
  // holds global (row = tid>>3 [+32i], kslot = (tid&7) ^ ((tid>>3)&7)).
  const int srow = tid >> 3;
  const int skslot = (tid & 7) ^ (srow & 7);
  const char* aP = (const char*)A + (size_t)(brow + srow) * KROWB + skslot * 16;
  const char* bP = (const char*)W + (size_t)(bcol + srow) * KROWB + skslot * 16;
  const int ldsw = wave * 1024;  // + lane*16 implicit in global_load_lds

  // fragment read: A row = wm*64 + mb*32 + (l&31); B row = wn*128 + nb*32 +
  // (l&31); kstep s: kslot = 2s + (l>>5); byte = row*128 + ((kslot^(row&7))<<4)
  const int ard = (wm * 64 + (lane & 31)) * 128;
  const int brd = 16384 + (wn * 128 + (lane & 31)) * 128;
  const int sx0 = (((lane >> 5) + 0) ^ (lane & 7)) << 4;
  const int sx1 = (((lane >> 5) + 2) ^ (lane & 7)) << 4;
  const int sx2 = (((lane >> 5) + 4) ^ (lane & 7)) << 4;
  const int sx3 = (((lane >> 5) + 6) ^ (lane & 7)) << 4;

  f32x16 acc[2][4];
#pragma unroll
  for (int m = 0; m < 2; ++m)
#pragma unroll
    for (int n = 0; n < 4; ++n)
      acc[m][n] = (f32x16){0.f, 0.f, 0.f, 0.f, 0.f, 0.f, 0.f, 0.f,
                           0.f, 0.f, 0.f, 0.f, 0.f, 0.f, 0.f, 0.f};
  bf16x8 af0, af1, bq0, bq1, bq2, bq3;

  // prologue: stage tiles 0 (slot 0) and 1 (slot 1); vmcnt(12) -> tile 0 in.
  STAGE(0, aP, bP);
  STAGE(1, aP + 128, bP + 128);
  VMW12(); BAR();

  const char* aSp = aP + 256;  // tile 2
  const char* bSp = bP + 256;

  for (int tt = 0; tt < 60; tt += 3) {  // tiles 0..59, stage t+2
    KT(0, 2, aSp,       bSp,       1, VMW12());
    KT(1, 0, aSp + 128, bSp + 128, 1, VMW12());
    KT(2, 1, aSp + 256, bSp + 256, 1, VMW12());
    aSp += 384; bSp += 384;
  }
  // aSp now at tile 62. Peel tiles 60..63 (slots 0,1,2,0).
  KT(0, 2, aSp,       bSp,       1, VMW12());  // t=60 stages 62
  KT(1, 0, aSp + 128, bSp + 128, 1, VMW12());  // t=61 stages 63
  KT(2, 0, aSp, bSp, 0, VMW0());               // t=62
  KT(0, 0, aSp, bSp, 0, NOW());                // t=63

  // epilogue: 32x32 C/D layout col = lane&31, row = (reg&3)+8*(reg>>2)+4*(l>>5)
  const int r0 = brow + wm * 64 + 4 * (lane >> 5);
  const int c0 = bcol + wn * 128 + (lane & 31);
#pragma unroll
  for (int mb = 0; mb < 2; ++mb)
#pragma unroll
    for (int nb = 0; nb < 4; ++nb)
#pragma unroll
      for (int reg = 0; reg < 16; ++reg)
        Y[(size_t)(r0 + mb * 32 + (reg & 3) + 8 * (reg >> 2)) * OUT_DIM +
          (c0 + nb * 32)] = acc[mb][nb][reg];

  // fused column stats (full-K sum in registers -> correct variance).
  // lanes l and l^32 share a column; reduce then atomics from lane<32.
#pragma unroll
  for (int nb = 0; nb < 4; ++nb) {
    float s = 0.f, q = 0.f;
#pragma unroll
    for (int mb = 0; mb < 2; ++mb)
#pragma unroll
      for (int reg = 0; reg < 16; ++reg) {
        float v = acc[mb][nb][reg];
        s += v; q += v * v;
      }
    s += __shfl_xor(s, 32); q += __shfl_xor(q, 32);
    if (lane < 32) {
      atomicAdd(&sums[c0 + nb * 32], s);
      atomicAdd(&sqs[c0 + nb * 32], q);
    }
  }
}

// K3: batchnorm on Y in-place (Y already complete)
__global__ void bnorm(float* __restrict__ Y,
                      const float* __restrict__ sums, const float* __restrict__ sqs,
                      const float* __restrict__ gamma, const float* __restrict__ beta) {
  int e = (blockIdx.x * 256 + threadIdx.x) * 4;
  int c = e % OUT_DIM;
  float4 y = *(float4*)(Y + e);
  float4 s = *(const float4*)(sums + c);
  float4 q = *(const float4*)(sqs + c);
  float4 g = *(const float4*)(gamma + c);
  float4 bb = *(const float4*)(beta + c);
  const float invB = 1.0f / (float)BATCH;
  float m0 = s.x * invB, m1 = s.y * invB, m2 = s.z * invB, m3 = s.w * invB;
  float i0 = rsqrtf(q.x * invB - m0 * m0 + BN_EPS);
  float i1 = rsqrtf(q.y * invB - m1 * m1 + BN_EPS);
  float i2 = rsqrtf(q.z * invB - m2 * m2 + BN_EPS);
  float i3 = rsqrtf(q.w * invB - m3 * m3 + BN_EPS);
  y.x = g.x * (y.x - m0) * i0 + bb.x;
  y.y = g.y * (y.y - m1) * i1 + bb.y;
  y.z = g.z * (y.z - m2) * i2 + bb.z;
  y.w = g.w * (y.w - m3) * i3 + bb.w;
  *(float4*)(Y + e) = y;
}

extern "C" void kernel_launch(void* const* d_in, const int* in_sizes, int n_in,
                              void* d_out, int out_size, void* d_ws, size_t ws_size,
                              hipStream_t stream) {
  const float* x         = (const float*)d_in[0];
  const float* scale     = (const float*)d_in[1];
  const float* translate = (const float*)d_in[2];
  const float* ww        = (const float*)d_in[3];
  const float* bw        = (const float*)d_in[4];
  const float* gamma     = (const float*)d_in[5];
  const float* beta      = (const float*)d_in[6];
  float* out = (float*)d_out;

  char* ws = (char*)d_ws;
  unsigned short* A = (unsigned short*)ws;                 // 33,554,432 B
  unsigned short* W = (unsigned short*)(ws + 33554432);    // 16,777,216 B
  float* sums = (float*)(ws + 50331648);
  float* sqs  = sums + OUT_DIM;

  hipMemsetAsync(sums, 0, 2 * OUT_DIM * sizeof(float), stream);
  prep_act<<<(BATCH * IN_DIM) / 1024, 256, 0, stream>>>(x, scale, translate, A);
  prep_w<<<(OUT_DIM * IN_DIM) / 1024, 256, 0, stream>>>(ww, bw, W);
  gemm128x256<<<256, 256, 0, stream>>>(A, W, out, sums, sqs);
  bnorm<<<(BATCH * OUT_DIM) / 1024, 256, 0, stream>>>(out, sums, sqs, gamma, beta);
}